// Round 5
// baseline (368.325 us; speedup 1.0000x reference)
//
#include <hip/hip_runtime.h>
#include <hip/hip_bf16.h>

#define SEQ   512
#define BATCH 256
#define ZD    64
#define NW    4        // waves per block (per chain)
#define SLICE 16       // ZD / NW contraction slice per wave

__device__ __forceinline__ float lane_bcastf(float v, int i) {
  return __int_as_float(__builtin_amdgcn_readlane(__float_as_int(v), i));
}
__device__ __forceinline__ int lane_bcasti(int v, int i) {
  return __builtin_amdgcn_readlane(v, i);
}

// Workgroup barrier WITHOUT the vmcnt(0) drain __syncthreads() implies.
// LDS ordering needs only lgkmcnt(0) on the writer side before s_barrier;
// global-load prefetches (vmcnt) stay in flight across the barrier.
__device__ __forceinline__ void lds_barrier() {
  asm volatile("s_waitcnt lgkmcnt(0)\n\ts_barrier" ::: "memory");
}

// One chain per block of 256 threads (4 waves). Blocks 0..255: forward chain
// for batch b; blocks 256..511: backward chain for b-256. Wave w covers
// contraction slice [16w, 16w+16): per step 16 readlane + 16 FMA, partials
// reduced across waves through a double-buffered LDS buffer.
// Round-3/4 lesson: a 64-float per-lane T array never stays in VGPRs; a
// 16-float slice does.
__global__ __launch_bounds__(256, 2) void hmm_chains(
    const int*   __restrict__ inp,    // [SEQ, BATCH]
    const float* __restrict__ T,      // [ZD, ZD] row-major
    const float* __restrict__ pi,     // [ZD]
    const float* __restrict__ emit,   // [X, ZD]
    float* __restrict__ out_alpha,    // [SEQ, BATCH, ZD] fp32
    float* __restrict__ out_beta)     // [SEQ, BATCH, ZD] fp32
{
  const int lane = threadIdx.x & 63;
  const int wv   = threadIdx.x >> 6;
  const int blk  = blockIdx.x;
  const bool fwd = (blk < BATCH);
  const int b    = fwd ? blk : blk - BATCH;
  const int ibase = wv * SLICE;

  __shared__ float buf[2][NW][ZD];    // 2 KB, double-buffered partials

  // Preload the whole x-sequence into 8 lane-indexed registers:
  // xv[w] in lane l holds x[64w + l]. In-loop access is pure v_readlane.
  int xv[8];
  #pragma unroll
  for (int w = 0; w < 8; ++w)
    xv[w] = inp[(w * 64 + lane) * BATCH + b];

  // Per-wave T slice (16 floats -> stays in VGPRs).
  float Tw[SLICE];
  if (fwd) {
    #pragma unroll
    for (int k = 0; k < SLICE; ++k) Tw[k] = T[lane * ZD + ibase + k];  // T[l][i]
  } else {
    #pragma unroll
    for (int k = 0; k < SLICE; ++k) Tw[k] = T[(ibase + k) * ZD + lane]; // T[j][l]
  }

  if (fwd) {
    // alpha_t[l] = e_t[l] * sum_i alpha_{t-1}[i] * T[l][i]
    const int x0 = lane_bcasti(xv[0], 0);
    float alpha = emit[x0 * ZD + lane] * pi[lane];
    if (wv == 0) out_alpha[(size_t)b * ZD + lane] = alpha;

    const int x1 = lane_bcasti(xv[0], 1);
    float e_next = emit[x1 * ZD + lane];          // e for t=1

    #pragma unroll
    for (int w = 0; w < 8; ++w) {
      const int xvw = xv[w];
      const int xvn = (w < 7) ? xv[w + 1] : xv[7];
      for (int idx = (w == 0) ? 1 : 0; idx < 64; ++idx) {
        const int t = w * 64 + idx;
        const float e_cur = e_next;
        // prefetch e for t+1 (x from registers; load stays in flight
        // across the barrier thanks to lds_barrier's no-vmcnt-drain)
        const int xsel = (idx < 63) ? xvw : xvn;
        const int xn   = lane_bcasti(xsel, (idx + 1) & 63);
        const float e_pf = emit[xn * ZD + lane];

        float a0 = 0.f, a1 = 0.f, a2 = 0.f, a3 = 0.f;
        #pragma unroll
        for (int k = 0; k < SLICE; k += 4) {
          a0 = fmaf(lane_bcastf(alpha, ibase + k + 0), Tw[k + 0], a0);
          a1 = fmaf(lane_bcastf(alpha, ibase + k + 1), Tw[k + 1], a1);
          a2 = fmaf(lane_bcastf(alpha, ibase + k + 2), Tw[k + 2], a2);
          a3 = fmaf(lane_bcastf(alpha, ibase + k + 3), Tw[k + 3], a3);
        }
        const int p = t & 1;
        buf[p][wv][lane] = (a0 + a1) + (a2 + a3);
        lds_barrier();
        const float y = (buf[p][0][lane] + buf[p][1][lane]) +
                        (buf[p][2][lane] + buf[p][3][lane]);
        alpha = e_cur * y;
        if (wv == 0) out_alpha[((size_t)t * BATCH + b) * ZD + lane] = alpha;
        e_next = e_pf;
      }
    }
  } else {
    // beta_t[l] = sum_j (e_{t+1}[j]*beta_{t+1}[j]) * T[j][l]
    float beta = 1.0f;
    if (wv == 0) out_beta[((size_t)(SEQ - 1) * BATCH + b) * ZD + lane] = beta;

    const int xL = lane_bcasti(xv[7], 63);
    float e_next = emit[xL * ZD + lane];          // e_{511}, for t=510

    #pragma unroll
    for (int w = 7; w >= 0; --w) {
      const int xvw = xv[w];
      for (int idx = (w == 7) ? 62 : 63; idx >= 0; --idx) {
        const int t = w * 64 + idx;
        const float e_cur = e_next;                  // e_{t+1}
        // prefetch e_t (consumed at iteration t-1); always in window w
        const int xn = lane_bcasti(xvw, idx);
        const float e_pf = emit[xn * ZD + lane];

        const float g = e_cur * beta;                // g[j] in lane j
        float a0 = 0.f, a1 = 0.f, a2 = 0.f, a3 = 0.f;
        #pragma unroll
        for (int k = 0; k < SLICE; k += 4) {
          a0 = fmaf(lane_bcastf(g, ibase + k + 0), Tw[k + 0], a0);
          a1 = fmaf(lane_bcastf(g, ibase + k + 1), Tw[k + 1], a1);
          a2 = fmaf(lane_bcastf(g, ibase + k + 2), Tw[k + 2], a2);
          a3 = fmaf(lane_bcastf(g, ibase + k + 3), Tw[k + 3], a3);
        }
        const int p = t & 1;
        buf[p][wv][lane] = (a0 + a1) + (a2 + a3);
        lds_barrier();
        beta = (buf[p][0][lane] + buf[p][1][lane]) +
               (buf[p][2][lane] + buf[p][3][lane]);
        if (wv == 0) out_beta[((size_t)t * BATCH + b) * ZD + lane] = beta;
        e_next = e_pf;
      }
    }
  }
}

// posterior[t,b,z] = alpha*beta / sum_z(alpha*beta). 8 z per lane (2x float4),
// 8 lanes per (t,b) row, xor-shuffle reduction within the 8-lane group.
__global__ __launch_bounds__(256) void posterior_k(
    const float* __restrict__ a,
    const float* __restrict__ bt,
    float*       __restrict__ p)
{
  const int tid = blockIdx.x * 256 + threadIdx.x;
  const size_t base = (size_t)tid * 8;

  const float4 va0 = *reinterpret_cast<const float4*>(a  + base);
  const float4 va1 = *reinterpret_cast<const float4*>(a  + base + 4);
  const float4 vb0 = *reinterpret_cast<const float4*>(bt + base);
  const float4 vb1 = *reinterpret_cast<const float4*>(bt + base + 4);

  const float p0 = va0.x * vb0.x;
  const float p1 = va0.y * vb0.y;
  const float p2 = va0.z * vb0.z;
  const float p3 = va0.w * vb0.w;
  const float p4 = va1.x * vb1.x;
  const float p5 = va1.y * vb1.y;
  const float p6 = va1.z * vb1.z;
  const float p7 = va1.w * vb1.w;

  float s = ((p0 + p1) + (p2 + p3)) + ((p4 + p5) + (p6 + p7));
  s += __shfl_xor(s, 1);
  s += __shfl_xor(s, 2);
  s += __shfl_xor(s, 4);
  const float inv = 1.0f / s;

  float4 o0, o1;
  o0.x = p0 * inv; o0.y = p1 * inv; o0.z = p2 * inv; o0.w = p3 * inv;
  o1.x = p4 * inv; o1.y = p5 * inv; o1.z = p6 * inv; o1.w = p7 * inv;
  *reinterpret_cast<float4*>(p + base)     = o0;
  *reinterpret_cast<float4*>(p + base + 4) = o1;
}

extern "C" void kernel_launch(void* const* d_in, const int* in_sizes, int n_in,
                              void* d_out, int out_size, void* d_ws, size_t ws_size,
                              hipStream_t stream) {
  const int*   inp  = (const int*)  d_in[0];
  const float* T    = (const float*)d_in[1];
  const float* pi   = (const float*)d_in[2];
  const float* emit = (const float*)d_in[3];

  float* out = (float*)d_out;
  const size_t N = (size_t)SEQ * BATCH * ZD;   // 8388608 per output
  float* out_alpha = out;
  float* out_beta  = out + N;
  float* out_post  = out + 2 * N;

  hipLaunchKernelGGL(hmm_chains, dim3(2 * BATCH), dim3(256), 0, stream,
                     inp, T, pi, emit, out_alpha, out_beta);

  // 256 threads * 8 elems = 2048 elems/block
  hipLaunchKernelGGL(posterior_k, dim3((unsigned)(N / 2048)), dim3(256), 0, stream,
                     out_alpha, out_beta, out_post);
}

// Round 6
// 238.482 us; speedup vs baseline: 1.5445x; 1.5445x over previous
//
#include <hip/hip_runtime.h>
#include <hip/hip_bf16.h>

#define SEQ   512
#define BATCH 256
#define ZD    64

__device__ __forceinline__ float lane_bcastf(float v, int i) {
  return __int_as_float(__builtin_amdgcn_readlane(__float_as_int(v), i));
}
__device__ __forceinline__ int lane_bcasti(int v, int i) {
  return __builtin_amdgcn_readlane(v, i);
}

// 64 distinct scalar names t00..t77 (two octal digits). The literal 0##n is
// an OCTAL constant equal to the linear index: t45 <-> 045 = 4*8+5 = 37.
#define REP8(M,p)  M(p##0) M(p##1) M(p##2) M(p##3) M(p##4) M(p##5) M(p##6) M(p##7)
#define REP64(M)   REP8(M,0) REP8(M,1) REP8(M,2) REP8(M,3) \
                   REP8(M,4) REP8(M,5) REP8(M,6) REP8(M,7)

#define TDECL(n)  float t##n;
#define TLOADF(n) t##n = Trp[0##n];          // T[lane][i], i = 0##n
#define TLOADB(n) t##n = Tcp[(0##n) * ZD];   // T[j][lane], j = 0##n
// Accumulate into 4 chains (constant index -> SROA keeps acc in registers).
#define TFMA(n)   acc[(0##n) & 3] = fmaf(lane_bcastf(vbc, 0##n), t##n, acc[(0##n) & 3]);
// Opaque register pin: named SSA scalars (NOT array elements -> no alloca).
// After this, LICM cannot re-sink the loads into the loop (rounds 3/4 failure).
#define TPIN(p)   asm volatile("" : "+v"(t##p##0), "+v"(t##p##1), "+v"(t##p##2), \
                                    "+v"(t##p##3), "+v"(t##p##4), "+v"(t##p##5), \
                                    "+v"(t##p##6), "+v"(t##p##7));
#define TPIN_ALL  TPIN(0) TPIN(1) TPIN(2) TPIN(3) TPIN(4) TPIN(5) TPIN(6) TPIN(7)

// One wave (64 lanes = 64 z-states) per chain; blocks 0..255 forward,
// 256..511 backward. No LDS, no barriers: shortest per-step critical path.
// (Round 5's 4-wave split raised VALUBusy 17->45% but was flat on time:
// the LDS+barrier round-trip replaced the issue-width win.)
__global__ __launch_bounds__(64, 1) void hmm_chains(
    const int*   __restrict__ inp,    // [SEQ, BATCH]
    const float* __restrict__ T,      // [ZD, ZD] row-major
    const float* __restrict__ pi,     // [ZD]
    const float* __restrict__ emit,   // [X, ZD]
    float* __restrict__ out_alpha,    // [SEQ, BATCH, ZD] fp32
    float* __restrict__ out_beta)     // [SEQ, BATCH, ZD] fp32
{
  const int lane = threadIdx.x;
  const int blk  = blockIdx.x;
  const bool fwd = (blk < BATCH);
  const int b    = fwd ? blk : blk - BATCH;

  // Whole x-sequence in 8 lane-indexed VGPRs: xv[w] lane l = x[64w + l].
  // In-loop access is a single v_readlane (uniform SGPR) -> zero per-step loads.
  int xv[8];
  #pragma unroll
  for (int w = 0; w < 8; ++w)
    xv[w] = inp[(w * 64 + lane) * BATCH + b];

  REP64(TDECL)

  if (fwd) {
    // alpha_t[l] = e_t[l] * sum_i alpha_{t-1}[i] * T[l][i]
    const float* Trp = T + lane * ZD;
    REP64(TLOADF)
    TPIN_ALL

    const int x0 = lane_bcasti(xv[0], 0);
    float alpha = emit[x0 * ZD + lane] * pi[lane];
    float* op = out_alpha + (size_t)b * ZD + lane;
    *op = alpha;
    op += BATCH * ZD;

    #pragma unroll
    for (int w = 0; w < 8; ++w) {
      const int xvw = xv[w];
      #pragma unroll 1                 // keep body (~1.2 KB) inside L1I
      for (int idx = (w == 0) ? 1 : 0; idx < 64; ++idx) {
        const int   xt = lane_bcasti(xvw, idx);   // x_t (uniform)
        const float e  = emit[xt * ZD + lane];    // issued here, used ~260cyc later
        float acc[4] = {0.f, 0.f, 0.f, 0.f};
        const float vbc = alpha;
        REP64(TFMA)                               // 64 readlane + 64 fma
        alpha = e * ((acc[0] + acc[1]) + (acc[2] + acc[3]));
        *op = alpha;
        op += BATCH * ZD;
      }
    }
  } else {
    // beta_t[l] = sum_j (e_{t+1}[j]*beta_{t+1}[j]) * T[j][l]
    const float* Tcp = T + lane;
    REP64(TLOADB)
    TPIN_ALL

    float beta = 1.0f;
    float* op = out_beta + ((size_t)(SEQ - 1) * BATCH + b) * ZD + lane;
    *op = beta;
    op -= BATCH * ZD;

    const int xL = lane_bcasti(xv[7], 63);
    float e_next = emit[xL * ZD + lane];          // e_{511}, consumed at t=510

    #pragma unroll
    for (int w = 7; w >= 0; --w) {
      const int xvw = xv[w];
      #pragma unroll 1
      for (int idx = (w == 7) ? 62 : 63; idx >= 0; --idx) {
        const int   xt   = lane_bcasti(xvw, idx); // x_t, e for next iteration
        const float e_pf = emit[xt * ZD + lane];
        const float vbc  = e_next * beta;         // g[j] broadcast source
        float acc[4] = {0.f, 0.f, 0.f, 0.f};
        REP64(TFMA)
        beta = (acc[0] + acc[1]) + (acc[2] + acc[3]);
        *op = beta;
        op -= BATCH * ZD;
        e_next = e_pf;
      }
    }
  }
}

// posterior[t,b,z] = alpha*beta / sum_z(alpha*beta). 8 z per lane (2x float4),
// 8 lanes per (t,b) row, xor-shuffle reduction within the 8-lane group.
__global__ __launch_bounds__(256) void posterior_k(
    const float* __restrict__ a,
    const float* __restrict__ bt,
    float*       __restrict__ p)
{
  const int tid = blockIdx.x * 256 + threadIdx.x;
  const size_t base = (size_t)tid * 8;

  const float4 va0 = *reinterpret_cast<const float4*>(a  + base);
  const float4 va1 = *reinterpret_cast<const float4*>(a  + base + 4);
  const float4 vb0 = *reinterpret_cast<const float4*>(bt + base);
  const float4 vb1 = *reinterpret_cast<const float4*>(bt + base + 4);

  const float p0 = va0.x * vb0.x;
  const float p1 = va0.y * vb0.y;
  const float p2 = va0.z * vb0.z;
  const float p3 = va0.w * vb0.w;
  const float p4 = va1.x * vb1.x;
  const float p5 = va1.y * vb1.y;
  const float p6 = va1.z * vb1.z;
  const float p7 = va1.w * vb1.w;

  float s = ((p0 + p1) + (p2 + p3)) + ((p4 + p5) + (p6 + p7));
  s += __shfl_xor(s, 1);
  s += __shfl_xor(s, 2);
  s += __shfl_xor(s, 4);
  const float inv = 1.0f / s;

  float4 o0, o1;
  o0.x = p0 * inv; o0.y = p1 * inv; o0.z = p2 * inv; o0.w = p3 * inv;
  o1.x = p4 * inv; o1.y = p5 * inv; o1.z = p6 * inv; o1.w = p7 * inv;
  *reinterpret_cast<float4*>(p + base)     = o0;
  *reinterpret_cast<float4*>(p + base + 4) = o1;
}

extern "C" void kernel_launch(void* const* d_in, const int* in_sizes, int n_in,
                              void* d_out, int out_size, void* d_ws, size_t ws_size,
                              hipStream_t stream) {
  const int*   inp  = (const int*)  d_in[0];
  const float* T    = (const float*)d_in[1];
  const float* pi   = (const float*)d_in[2];
  const float* emit = (const float*)d_in[3];

  float* out = (float*)d_out;
  const size_t N = (size_t)SEQ * BATCH * ZD;   // 8388608 per output
  float* out_alpha = out;
  float* out_beta  = out + N;
  float* out_post  = out + 2 * N;

  hipLaunchKernelGGL(hmm_chains, dim3(2 * BATCH), dim3(64), 0, stream,
                     inp, T, pi, emit, out_alpha, out_beta);

  hipLaunchKernelGGL(posterior_k, dim3((unsigned)(N / 2048)), dim3(256), 0, stream,
                     out_alpha, out_beta, out_post);
}